// Round 6
// baseline (245.422 us; speedup 1.0000x reference)
//
#include <hip/hip_runtime.h>
#include <hip/hip_fp16.h>

typedef _Float16 f16;
typedef _Float16 half4 __attribute__((ext_vector_type(4)));
typedef _Float16 half8 __attribute__((ext_vector_type(8)));
typedef float f32x4 __attribute__((ext_vector_type(4)));

#define BATCH 16
#define L 1024
#define H 1024

// ---------------- f32 -> fp16 bulk convert (8 elems/thread) ----------------
__global__ __launch_bounds__(256) void cvt_f32_f16(const float* __restrict__ in,
                                                   f16* __restrict__ out, long n) {
  long i = ((long)blockIdx.x * 256 + threadIdx.x) * 8;
  const long stride = (long)gridDim.x * 256 * 8;
  for (; i < n; i += stride) {
    const float4 a = *(const float4*)(&in[i]);
    const float4 b = *(const float4*)(&in[i + 4]);
    half8 h;
    h[0] = (f16)a.x; h[1] = (f16)a.y; h[2] = (f16)a.z; h[3] = (f16)a.w;
    h[4] = (f16)b.x; h[5] = (f16)b.y; h[6] = (f16)b.z; h[7] = (f16)b.w;
    *(half8*)(&out[i]) = h;
  }
}

// ------- y [b,m,h] f32 -> Yh [b,m,h] fp16 AND Yt [b,h,m] fp16 -------
__global__ __launch_bounds__(256) void transpose_y(const float* __restrict__ Y,
                                                   f16* __restrict__ Yh,
                                                   f16* __restrict__ Yt) {
  __shared__ f16 tile[32][33];
  const int b = blockIdx.z;
  const float* Yb = Y + (long)b * L * H;
  f16* Yhb = Yh + (long)b * L * H;
  f16* Ytb = Yt + (long)b * L * H;
  const int h0 = blockIdx.x * 32, m0 = blockIdx.y * 32;
  const int tx = threadIdx.x, ty = threadIdx.y;
  #pragma unroll
  for (int i = ty; i < 32; i += 8) {
    const f16 hv = (f16)Yb[(long)(m0 + i) * H + h0 + tx];
    tile[i][tx] = hv;
    Yhb[(long)(m0 + i) * H + h0 + tx] = hv;
  }
  __syncthreads();
  #pragma unroll
  for (int i = ty; i < 32; i += 8)
    Ytb[(long)(h0 + i) * L + m0 + tx] = tile[tx][i];
}

// =====================================================================
// 256x256 tile, BK=32, 8 waves (2 wm x 4 wn, 128x64/wave), 4-buf LDS
// (128KB), fine 2-phase schedule per K-tile, counted vmcnt(4), staging
// distance 2, fresh per-phase fragment regs + bv parity ping-pong.
// Phase A: read bv(4)+av(4 lo) | stage A(t+2) | bar | 16 MFMA | bar
// Phase B: read av(4 hi)       | stage B(t+2) | bar | 16 MFMA |
//          vmcnt(4) | bar
// Safety: buf (t+2)&3 last read iter t-2 (>=4 barriers ago). vmcnt(4)
// at end of iter t drains tile t+1's 4 loads (issued iter t-1, ~2
// K-tiles ago), leaves tile t+2's 4 in flight.
// =====================================================================
#define GLD16(g, l)                                           \
  __builtin_amdgcn_global_load_lds(                           \
      (const __attribute__((address_space(1))) void*)(g),     \
      (__attribute__((address_space(3))) void*)(l), 16, 0, 0)

template <int EPI, int TAG>
__global__ __launch_bounds__(512, 2) void gemm256(
    const f16* __restrict__ Ap, const f16* __restrict__ Bp,
    const float* __restrict__ bias, void* __restrict__ Cp,
    long sA, long sB, long sC, int nxyShift) {
  __shared__ f16 lds[4 * 16384];  // 4 bufs x (A 16KB + B 16KB) = 128 KB
  constexpr int N = 1024, K = 1024, NT = 32;

  const int tid = threadIdx.x;
  const int lane = tid & 63;
  const int wid = tid >> 6;   // 0..7
  const int wm = wid >> 2;    // 0..1  (128-row band)
  const int wn = wid & 3;     // 0..3  (64-col band)

  // XCD-aware bijective swizzle (nwg % 8 == 0 for all launches)
  const int nwg = gridDim.x;
  const int orig = blockIdx.x;
  const int wg = (orig & 7) * (nwg >> 3) + (orig >> 3);
  const int bz = wg >> nxyShift;
  const int rxy = wg & ((1 << nxyShift) - 1);
  const int bx = rxy & 3;      // N=1024 -> 4 col blocks of 256
  const int by = rxy >> 2;
  const int row0 = by * 256, col0 = bx * 256;

  const f16* A = Ap + (long)bz * sA;
  const f16* B = Bp + (long)bz * sB;

  // ---- staging addressing (chunk = 16 rows x 64B = 1KB; proven R5) ----
  const int srow = lane >> 2;                       // row in chunk
  const int sslot = (lane & 3) ^ ((lane >> 3) & 3); // pre-swizzled src slot
  const f16* gA0 = A + (long)(row0 + wid * 32 + srow) * K + sslot * 8;
  const f16* gA1 = A + (long)(row0 + wid * 32 + 16 + srow) * K + sslot * 8;
  const f16* gB0 = B + (long)(col0 + wid * 32 + srow) * K + sslot * 8;
  const f16* gB1 = B + (long)(col0 + wid * 32 + 16 + srow) * K + sslot * 8;
  char* ldsw = (char*)lds;

  // ---- fragment read addressing (read-side XOR matches staging) ----
  const int fr = lane & 15, fq = lane >> 4;
  const int rsw = (fq ^ ((fr >> 1) & 3)) << 4;      // swizzled 16B slot
  const int aByte = (wm * 128 + fr) * 64 + rsw;
  const int bByte = (wn * 64 + fr) * 64 + rsw;
  const char* ldsr = (const char*)lds;

  f32x4 acc[8][4];
  #pragma unroll
  for (int i = 0; i < 8; ++i)
    #pragma unroll
    for (int j = 0; j < 4; ++j)
      acc[i][j] = (f32x4){0.f, 0.f, 0.f, 0.f};

  // ---- prologue: stage tiles 0,1 -> bufs 0,1 ----
  #pragma unroll
  for (int p = 0; p < 2; ++p) {
    char* b = ldsw + p * 32768;
    GLD16(gA0, b + wid * 2048);
    GLD16(gA1, b + wid * 2048 + 1024);
    GLD16(gB0, b + 16384 + wid * 2048);
    GLD16(gB1, b + 16384 + wid * 2048 + 1024);
    gA0 += 32; gA1 += 32; gB0 += 32; gB1 += 32;
  }
  asm volatile("s_waitcnt vmcnt(4)" ::: "memory");
  __builtin_amdgcn_s_barrier();
  __builtin_amdgcn_sched_barrier(0);

  half8 bvE[4], bvO[4];  // bv parity ping-pong (kills WAR on bv)

  auto ktile = [&](int T, half8(&BV)[4]) {
    const char* rb = ldsr + (T & 3) * 32768;
    char* wb = ldsw + ((T + 2) & 3) * 32768;
    const bool pf = (T + 2) < NT;
    // ---------------- phase A ----------------
    half8 av0[4];
    #pragma unroll
    for (int j = 0; j < 4; ++j)
      BV[j] = *(const half8*)(rb + 16384 + bByte + j * 1024);
    #pragma unroll
    for (int i = 0; i < 4; ++i)
      av0[i] = *(const half8*)(rb + aByte + i * 1024);
    if (pf) {
      GLD16(gA0, wb + wid * 2048);
      GLD16(gA1, wb + wid * 2048 + 1024);
    }
    __builtin_amdgcn_sched_barrier(0);
    __builtin_amdgcn_s_barrier();
    __builtin_amdgcn_sched_barrier(0);
    __builtin_amdgcn_s_setprio(1);
    #pragma unroll
    for (int i = 0; i < 4; ++i)
      #pragma unroll
      for (int j = 0; j < 4; ++j)
        acc[i][j] = __builtin_amdgcn_mfma_f32_16x16x32_f16(av0[i], BV[j],
                                                           acc[i][j], 0, 0, 0);
    __builtin_amdgcn_s_setprio(0);
    __builtin_amdgcn_sched_barrier(0);
    __builtin_amdgcn_s_barrier();
    __builtin_amdgcn_sched_barrier(0);
    // ---------------- phase B ----------------
    half8 av1[4];
    #pragma unroll
    for (int i = 0; i < 4; ++i)
      av1[i] = *(const half8*)(rb + aByte + 4096 + i * 1024);
    if (pf) {
      GLD16(gB0, wb + 16384 + wid * 2048);
      GLD16(gB1, wb + 16384 + wid * 2048 + 1024);
      gA0 += 32; gA1 += 32; gB0 += 32; gB1 += 32;
    }
    __builtin_amdgcn_sched_barrier(0);
    __builtin_amdgcn_s_barrier();
    __builtin_amdgcn_sched_barrier(0);
    __builtin_amdgcn_s_setprio(1);
    #pragma unroll
    for (int i = 0; i < 4; ++i)
      #pragma unroll
      for (int j = 0; j < 4; ++j)
        acc[4 + i][j] = __builtin_amdgcn_mfma_f32_16x16x32_f16(av1[i], BV[j],
                                                               acc[4 + i][j],
                                                               0, 0, 0);
    __builtin_amdgcn_s_setprio(0);
    __builtin_amdgcn_sched_barrier(0);
    if (T + 2 < NT)
      asm volatile("s_waitcnt vmcnt(4)" ::: "memory");
    else if (T + 1 < NT)
      asm volatile("s_waitcnt vmcnt(0)" ::: "memory");
    if (T + 1 < NT) {
      __builtin_amdgcn_s_barrier();
      __builtin_amdgcn_sched_barrier(0);
    }
  };

  for (int t = 0; t < NT; t += 2) {
    ktile(t, bvE);
    ktile(t + 1, bvO);
  }

  // ---------------- epilogue ----------------
  if (EPI == 0) {
    f16* C = (f16*)Cp + (long)bz * sC;
    #pragma unroll
    for (int j = 0; j < 4; ++j) {
      const int col = col0 + wn * 64 + j * 16 + fr;
      const float bvs = bias[col];
      #pragma unroll
      for (int i = 0; i < 8; ++i) {
        const int rowb = row0 + wm * 128 + i * 16 + fq * 4;
        #pragma unroll
        for (int r = 0; r < 4; ++r) {
          float v = acc[i][j][r] + bvs;
          v = v > 0.f ? v : 0.f;
          C[(long)(rowb + r) * N + col] = (f16)v;
        }
      }
    }
  } else {
    float* C = (float*)Cp + (long)bz * sC;
    #pragma unroll
    for (int j = 0; j < 4; ++j) {
      const int col = col0 + wn * 64 + j * 16 + fr;
      #pragma unroll
      for (int i = 0; i < 8; ++i) {
        const int rowb = row0 + wm * 128 + i * 16 + fq * 4;
        #pragma unroll
        for (int r = 0; r < 4; ++r)
          C[(long)(rowb + r) * N + col] = acc[i][j][r];
      }
    }
  }
}

// ---------------- masked row softmax: f32 scores -> fp16 alpha ----------------
__global__ __launch_bounds__(256) void softmax_rows(const float* __restrict__ S,
                                                    const int* __restrict__ mask,
                                                    f16* __restrict__ P) {
  const int b = blockIdx.y;
  const int l = blockIdx.x;
  const float* srow = S + ((long)b * L + l) * L;
  f16* prow = P + ((long)b * L + l) * L;
  const int* mrow = mask + b * L;
  const int t = threadIdx.x;

  const float4 v = *(const float4*)(&srow[t * 4]);
  const int4 mk = *(const int4*)(&mrow[t * 4]);
  const float x0 = mk.x ? -1e30f : v.x;
  const float x1 = mk.y ? -1e30f : v.y;
  const float x2 = mk.z ? -1e30f : v.z;
  const float x3 = mk.w ? -1e30f : v.w;

  float mx = fmaxf(fmaxf(x0, x1), fmaxf(x2, x3));
  #pragma unroll
  for (int off = 32; off >= 1; off >>= 1)
    mx = fmaxf(mx, __shfl_xor(mx, off));
  __shared__ float red[8];
  const int wid = t >> 6, lane = t & 63;
  if (lane == 0) red[wid] = mx;
  __syncthreads();
  mx = fmaxf(fmaxf(red[0], red[1]), fmaxf(red[2], red[3]));

  const float e0 = __expf(x0 - mx), e1 = __expf(x1 - mx);
  const float e2 = __expf(x2 - mx), e3 = __expf(x3 - mx);
  float s = e0 + e1 + e2 + e3;
  #pragma unroll
  for (int off = 32; off >= 1; off >>= 1)
    s += __shfl_xor(s, off);
  if (lane == 0) red[4 + wid] = s;
  __syncthreads();
  s = red[4] + red[5] + red[6] + red[7];
  const float inv = 1.f / s;
  half4 h;
  h[0] = (f16)(e0 * inv); h[1] = (f16)(e1 * inv);
  h[2] = (f16)(e2 * inv); h[3] = (f16)(e3 * inv);
  *(half4*)(&prow[t * 4]) = h;
}

extern "C" void kernel_launch(void* const* d_in, const int* in_sizes, int n_in,
                              void* d_out, int out_size, void* d_ws,
                              size_t ws_size, hipStream_t stream) {
  const float* x = (const float*)d_in[0];
  const float* y = (const float*)d_in[1];
  const int* ymask = (const int*)d_in[2];
  const float* W = (const float*)d_in[3];
  const float* bias = (const float*)d_in[4];
  float* out = (float*)d_out;

  // ws layout (162 MB):
  //   Wh 2MB | Yt 32MB | XYp 64MB | XYh 64MB (aliased by Sc after proj)
  char* ws = (char*)d_ws;
  f16* Wh = (f16*)(ws);
  f16* Yt = (f16*)(ws + (1L << 21));
  f16* XYp = (f16*)(ws + (1L << 21) + (1L << 25));
  f16* XYh = (f16*)(ws + (1L << 21) + (1L << 25) + (1L << 26));
  float* Sc = (float*)XYh;  // XYh dead after proj GEMM
  f16* Alpha = XYp;         // Xp half dead after scores GEMM

  f16* Xh = XYh;                        // rows [0, 16384)
  f16* Yh = XYh + (long)BATCH * L * H;  // rows [16384, 32768)

  cvt_f32_f16<<<512, 256, 0, stream>>>(W, Wh, (long)H * H);
  cvt_f32_f16<<<8192, 256, 0, stream>>>(x, Xh, (long)BATCH * L * H);
  transpose_y<<<dim3(32, 32, BATCH), dim3(32, 8), 0, stream>>>(y, Yh, Yt);

  // fused projection: [32768,1024] = relu(XYh @ Wh^T + b), fp16
  gemm256<0, 0><<<512, 512, 0, stream>>>(XYh, Wh, bias, XYp, 0, 0, 0, 9);

  // scores[b] = Xp[b] @ Yp[b]^T, f32
  gemm256<1, 1><<<256, 512, 0, stream>>>(XYp, XYp + (long)BATCH * L * H,
                                         nullptr, Sc, (long)L * H, (long)L * H,
                                         (long)L * L, 4);

  // alpha = softmax(mask(scores)), fp16 (into dead Xp region)
  softmax_rows<<<dim3(L, BATCH), 256, 0, stream>>>(Sc, ymask, Alpha);

  // out[b] = alpha[b] @ Yt[b]^T  == alpha[b] @ y[b]
  gemm256<1, 2><<<256, 512, 0, stream>>>(Alpha, Yt, nullptr, out, (long)L * L,
                                         (long)H * L, (long)L * H, 4);
}

// Round 7
// 224.801 us; speedup vs baseline: 1.0917x; 1.0917x over previous
//
#include <hip/hip_runtime.h>
#include <hip/hip_fp16.h>

typedef _Float16 f16;
typedef _Float16 half4 __attribute__((ext_vector_type(4)));
typedef _Float16 half8 __attribute__((ext_vector_type(8)));
typedef float f32x4 __attribute__((ext_vector_type(4)));

#define BATCH 16
#define L 1024
#define H 1024

// -------- f32 -> fp16 bulk convert: W (blocks [0,512)) + x (rest) --------
__global__ __launch_bounds__(256) void cvt_wx(const float* __restrict__ W,
                                              f16* __restrict__ Wh,
                                              const float* __restrict__ x,
                                              f16* __restrict__ Xh) {
  const float* src;
  f16* dst;
  long i;
  if (blockIdx.x < 512) {
    src = W; dst = Wh;
    i = (long)blockIdx.x * 2048 + threadIdx.x * 8;
  } else {
    src = x; dst = Xh;
    i = ((long)blockIdx.x - 512) * 2048 + threadIdx.x * 8;
  }
  const float4 a = *(const float4*)(&src[i]);
  const float4 b = *(const float4*)(&src[i + 4]);
  half8 h;
  h[0] = (f16)a.x; h[1] = (f16)a.y; h[2] = (f16)a.z; h[3] = (f16)a.w;
  h[4] = (f16)b.x; h[5] = (f16)b.y; h[6] = (f16)b.z; h[7] = (f16)b.w;
  *(half8*)(&dst[i]) = h;
}

// -- y [b,m,h] f32 -> Yh [b,m,h] fp16 AND Yt [b,h,m] fp16, vectorized --
// 64(h) x 32(m) tile per block, 256 threads. float4 reads, half4 stores.
__global__ __launch_bounds__(256) void transpose_y(const float* __restrict__ Y,
                                                   f16* __restrict__ Yh,
                                                   f16* __restrict__ Yt) {
  __shared__ f16 tile[64][36];  // [h][m], stride 36 f16 = 72B (8B aligned)
  const int b = blockIdx.z;
  const float* Yb = Y + (long)b * L * H;
  f16* Yhb = Yh + (long)b * L * H;
  f16* Ytb = Yt + (long)b * L * H;
  const int h0 = blockIdx.x * 64, m0 = blockIdx.y * 32;
  const int tid = threadIdx.x;

  const int hc = (tid & 15) * 4;   // h offset within tile (read phase)
  #pragma unroll
  for (int rr = 0; rr < 2; ++rr) {
    const int m = (tid >> 4) + rr * 16;  // m offset within tile
    const float4 v = *(const float4*)(&Yb[(long)(m0 + m) * H + h0 + hc]);
    half4 h4;
    h4[0] = (f16)v.x; h4[1] = (f16)v.y; h4[2] = (f16)v.z; h4[3] = (f16)v.w;
    *(half4*)(&Yhb[(long)(m0 + m) * H + h0 + hc]) = h4;
    tile[hc + 0][m] = h4[0];
    tile[hc + 1][m] = h4[1];
    tile[hc + 2][m] = h4[2];
    tile[hc + 3][m] = h4[3];
  }
  __syncthreads();
  const int m4 = (tid & 7) * 4;    // m offset (write phase)
  #pragma unroll
  for (int it = 0; it < 2; ++it) {
    const int hh = (tid >> 3) + it * 32;
    *(half4*)(&Ytb[(long)(h0 + hh) * L + m0 + m4]) =
        *(const half4*)(&tile[hh][m4]);
  }
}

// =====================================================================
// 256x128 tile GEMM, BK=32, 8 waves (wm 0..3 x wn 0..1, 64x64/wave),
// 3-slot LDS (72KB) -> 2 blocks/CU for cross-block phase overlap.
// C[M,1024] = A[M,1024] * B[1024,1024]^T, fp16 in.  [R5 proven best]
// Per K-32 step t: issue 3 gload_lds (step t+2 -> slot (t+2)%3) |
// 8 ds_read_b128 | setprio1 | 16 MFMA | setprio0 | vmcnt(3) | barrier.
// =====================================================================
#define GLD16(g, l)                                           \
  __builtin_amdgcn_global_load_lds(                           \
      (const __attribute__((address_space(1))) void*)(g),     \
      (__attribute__((address_space(3))) void*)(l), 16, 0, 0)

template <int EPI, int TAG>
__global__ __launch_bounds__(512, 4) void gemm128(
    const f16* __restrict__ Ap, const f16* __restrict__ Bp,
    const float* __restrict__ bias, void* __restrict__ Cp,
    long sA, long sB, long sC, int nxyShift) {
  __shared__ f16 lds[3 * 12288];  // 3 slots x (A 16KB + B 8KB) = 72 KB
  constexpr int N = 1024, K = 1024, NT = 32;

  const int tid = threadIdx.x;
  const int lane = tid & 63;
  const int wid = tid >> 6;   // 0..7
  const int wm = wid >> 1;    // 0..3  (64-row band)
  const int wn = wid & 1;     // 0..1  (64-col band)

  // XCD-aware bijective swizzle (nwg % 8 == 0 for all launches)
  const int nwg = gridDim.x;
  const int orig = blockIdx.x;
  const int wg = (orig & 7) * (nwg >> 3) + (orig >> 3);
  const int bz = wg >> nxyShift;
  const int rxy = wg & ((1 << nxyShift) - 1);
  const int bx = rxy & 7;      // N=1024 -> 8 col blocks of 128
  const int by = rxy >> 3;
  const int row0 = by * 256, col0 = bx * 128;

  const f16* A = Ap + (long)bz * sA;
  const f16* B = Bp + (long)bz * sB;

  // ---- staging addressing (chunk = 16 rows x 64B = 1KB) ----
  const int srow = lane >> 2;                       // row in chunk
  const int sslot = (lane & 3) ^ ((lane >> 3) & 3); // pre-swizzled src slot
  const f16* gA0 = A + (long)(row0 + wid * 32 + srow) * K + sslot * 8;
  const f16* gA1 = A + (long)(row0 + wid * 32 + 16 + srow) * K + sslot * 8;
  const f16* gB0 = B + (long)(col0 + wid * 16 + srow) * K + sslot * 8;
  char* ldsw = (char*)lds;

  // ---- fragment read addressing (read-side XOR matches staging) ----
  const int fr = lane & 15, fq = lane >> 4;
  const int rsw = (fq ^ ((fr >> 1) & 3)) << 4;      // swizzled 16B slot
  const int aByte = (wm * 64 + fr) * 64 + rsw;
  const int bByte = (wn * 64 + fr) * 64 + rsw;
  const char* ldsr = (const char*)lds;

  f32x4 acc[4][4];
  #pragma unroll
  for (int i = 0; i < 4; ++i)
    #pragma unroll
    for (int j = 0; j < 4; ++j)
      acc[i][j] = (f32x4){0.f, 0.f, 0.f, 0.f};

  // ---- prologue: stage steps 0,1 -> slots 0,1 ----
  #pragma unroll
  for (int p = 0; p < 2; ++p) {
    char* sb = ldsw + p * 24576;
    GLD16(gA0, sb + wid * 2048);
    GLD16(gA1, sb + wid * 2048 + 1024);
    GLD16(gB0, sb + 16384 + wid * 1024);
    gA0 += 32; gA1 += 32; gB0 += 32;
  }
  asm volatile("s_waitcnt vmcnt(3)" ::: "memory");
  __builtin_amdgcn_s_barrier();
  __builtin_amdgcn_sched_barrier(0);

  int cb = 0, pb = 2 * 24576;
  for (int t = 0; t < NT; ++t) {
    // ---- issue prefetch for step t+2 ----
    if (t + 2 < NT) {
      char* sb = ldsw + pb;
      GLD16(gA0, sb + wid * 2048);
      GLD16(gA1, sb + wid * 2048 + 1024);
      GLD16(gB0, sb + 16384 + wid * 1024);
      gA0 += 32; gA1 += 32; gB0 += 32;
    }
    // ---- compute step t from slot t%3 ----
    const char* base = ldsr + cb;
    half8 av[4], bv[4];
    #pragma unroll
    for (int j = 0; j < 4; ++j)
      bv[j] = *(const half8*)(base + 16384 + bByte + j * 1024);
    #pragma unroll
    for (int i = 0; i < 4; ++i)
      av[i] = *(const half8*)(base + aByte + i * 1024);
    __builtin_amdgcn_s_setprio(1);
    #pragma unroll
    for (int i = 0; i < 4; ++i)
      #pragma unroll
      for (int j = 0; j < 4; ++j)
        acc[i][j] = __builtin_amdgcn_mfma_f32_16x16x32_f16(av[i], bv[j],
                                                           acc[i][j], 0, 0, 0);
    __builtin_amdgcn_s_setprio(0);
    // ---- boundary: counted drain + single barrier ----
    if (t < NT - 1) {
      __builtin_amdgcn_sched_barrier(0);
      if (t <= NT - 3)
        asm volatile("s_waitcnt vmcnt(3)" ::: "memory");
      else
        asm volatile("s_waitcnt vmcnt(0)" ::: "memory");
      __builtin_amdgcn_s_barrier();
      __builtin_amdgcn_sched_barrier(0);
      cb = (cb == 49152) ? 0 : cb + 24576;
      pb = (pb == 49152) ? 0 : pb + 24576;
    }
  }

  // ---------------- epilogue ----------------
  if (EPI == 0) {
    f16* C = (f16*)Cp + (long)bz * sC;
    #pragma unroll
    for (int j = 0; j < 4; ++j) {
      const int col = col0 + wn * 64 + j * 16 + fr;
      const float bvs = bias[col];
      #pragma unroll
      for (int i = 0; i < 4; ++i) {
        const int rowb = row0 + wm * 64 + i * 16 + fq * 4;
        #pragma unroll
        for (int r = 0; r < 4; ++r) {
          float v = acc[i][j][r] + bvs;
          v = v > 0.f ? v : 0.f;
          C[(long)(rowb + r) * N + col] = (f16)v;
        }
      }
    }
  } else {
    float* C = (float*)Cp + (long)bz * sC;
    #pragma unroll
    for (int j = 0; j < 4; ++j) {
      const int col = col0 + wn * 64 + j * 16 + fr;
      #pragma unroll
      for (int i = 0; i < 4; ++i) {
        const int rowb = row0 + wm * 64 + i * 16 + fq * 4;
        #pragma unroll
        for (int r = 0; r < 4; ++r)
          C[(long)(rowb + r) * N + col] = acc[i][j][r];
      }
    }
  }
}

// ---------------- masked row softmax: f32 scores -> fp16 alpha ----------------
__global__ __launch_bounds__(256) void softmax_rows(const float* __restrict__ S,
                                                    const int* __restrict__ mask,
                                                    f16* __restrict__ P) {
  const int b = blockIdx.y;
  const int l = blockIdx.x;
  const float* srow = S + ((long)b * L + l) * L;
  f16* prow = P + ((long)b * L + l) * L;
  const int* mrow = mask + b * L;
  const int t = threadIdx.x;

  const float4 v = *(const float4*)(&srow[t * 4]);
  const int4 mk = *(const int4*)(&mrow[t * 4]);
  const float x0 = mk.x ? -1e30f : v.x;
  const float x1 = mk.y ? -1e30f : v.y;
  const float x2 = mk.z ? -1e30f : v.z;
  const float x3 = mk.w ? -1e30f : v.w;

  float mx = fmaxf(fmaxf(x0, x1), fmaxf(x2, x3));
  #pragma unroll
  for (int off = 32; off >= 1; off >>= 1)
    mx = fmaxf(mx, __shfl_xor(mx, off));
  __shared__ float red[8];
  const int wid = t >> 6, lane = t & 63;
  if (lane == 0) red[wid] = mx;
  __syncthreads();
  mx = fmaxf(fmaxf(red[0], red[1]), fmaxf(red[2], red[3]));

  const float e0 = __expf(x0 - mx), e1 = __expf(x1 - mx);
  const float e2 = __expf(x2 - mx), e3 = __expf(x3 - mx);
  float s = e0 + e1 + e2 + e3;
  #pragma unroll
  for (int off = 32; off >= 1; off >>= 1)
    s += __shfl_xor(s, off);
  if (lane == 0) red[4 + wid] = s;
  __syncthreads();
  s = red[4] + red[5] + red[6] + red[7];
  const float inv = 1.f / s;
  half4 h;
  h[0] = (f16)(e0 * inv); h[1] = (f16)(e1 * inv);
  h[2] = (f16)(e2 * inv); h[3] = (f16)(e3 * inv);
  *(half4*)(&prow[t * 4]) = h;
}

extern "C" void kernel_launch(void* const* d_in, const int* in_sizes, int n_in,
                              void* d_out, int out_size, void* d_ws,
                              size_t ws_size, hipStream_t stream) {
  const float* x = (const float*)d_in[0];
  const float* y = (const float*)d_in[1];
  const int* ymask = (const int*)d_in[2];
  const float* W = (const float*)d_in[3];
  const float* bias = (const float*)d_in[4];
  float* out = (float*)d_out;

  // ws layout (162 MB):
  //   Wh 2MB | Yt 32MB | XYp 64MB | XYh 64MB (aliased by Sc after proj)
  char* ws = (char*)d_ws;
  f16* Wh = (f16*)(ws);
  f16* Yt = (f16*)(ws + (1L << 21));
  f16* XYp = (f16*)(ws + (1L << 21) + (1L << 25));
  f16* XYh = (f16*)(ws + (1L << 21) + (1L << 25) + (1L << 26));
  float* Sc = (float*)XYh;  // XYh dead after proj GEMM
  f16* Alpha = XYp;         // Xp half dead after scores GEMM

  f16* Xh = XYh;                        // rows [0, 16384)
  f16* Yh = XYh + (long)BATCH * L * H;  // rows [16384, 32768)

  cvt_wx<<<512 + 8192, 256, 0, stream>>>(W, Wh, x, Xh);
  transpose_y<<<dim3(16, 32, BATCH), 256, 0, stream>>>(y, Yh, Yt);

  // fused projection: [32768,1024] = relu(XYh @ Wh^T + b), fp16
  gemm128<0, 0><<<1024, 512, 0, stream>>>(XYh, Wh, bias, XYp, 0, 0, 0, 10);

  // scores[b] = Xp[b] @ Yp[b]^T, f32
  gemm128<1, 1><<<512, 512, 0, stream>>>(XYp, XYp + (long)BATCH * L * H,
                                         nullptr, Sc, (long)L * H, (long)L * H,
                                         (long)L * L, 5);

  // alpha = softmax(mask(scores)), fp16 (into dead Xp region)
  softmax_rows<<<dim3(L, BATCH), 256, 0, stream>>>(Sc, ymask, Alpha);

  // out[b] = alpha[b] @ Yt[b]^T  == alpha[b] @ y[b]
  gemm128<1, 2><<<512, 512, 0, stream>>>(Alpha, Yt, nullptr, out, (long)L * L,
                                         (long)H * L, (long)L * H, 5);
}

// Round 8
// 220.127 us; speedup vs baseline: 1.1149x; 1.0212x over previous
//
#include <hip/hip_runtime.h>
#include <hip/hip_fp16.h>

typedef _Float16 f16;
typedef _Float16 half4 __attribute__((ext_vector_type(4)));
typedef _Float16 half8 __attribute__((ext_vector_type(8)));
typedef float f32x4 __attribute__((ext_vector_type(4)));

#define BATCH 16
#define L 1024
#define H 1024

// -------- f32 -> fp16 bulk convert: W (blocks [0,512)) + x (rest) --------
__global__ __launch_bounds__(256) void cvt_wx(const float* __restrict__ W,
                                              f16* __restrict__ Wh,
                                              const float* __restrict__ x,
                                              f16* __restrict__ Xh) {
  const float* src;
  f16* dst;
  long i;
  if (blockIdx.x < 512) {
    src = W; dst = Wh;
    i = (long)blockIdx.x * 2048 + threadIdx.x * 8;
  } else {
    src = x; dst = Xh;
    i = ((long)blockIdx.x - 512) * 2048 + threadIdx.x * 8;
  }
  const float4 a = *(const float4*)(&src[i]);
  const float4 b = *(const float4*)(&src[i + 4]);
  half8 h;
  h[0] = (f16)a.x; h[1] = (f16)a.y; h[2] = (f16)a.z; h[3] = (f16)a.w;
  h[4] = (f16)b.x; h[5] = (f16)b.y; h[6] = (f16)b.z; h[7] = (f16)b.w;
  *(half8*)(&dst[i]) = h;
}

// ---- per-batch mask prefix scan: posx (exclusive), midxg, cnt ----
__global__ __launch_bounds__(256) void mask_scan(const int* __restrict__ mask,
                                                 int* __restrict__ posx,
                                                 int* __restrict__ midxg,
                                                 int* __restrict__ cntA) {
  const int b = blockIdx.x;
  const int t = threadIdx.x;
  const int4 mk = *(const int4*)(&mask[b * 1024 + t * 4]);
  const int f0 = (mk.x == 0), f1 = (mk.y == 0);
  const int f2 = (mk.z == 0), f3 = (mk.w == 0);
  const int s = f0 + f1 + f2 + f3;
  int v = s;
  const int lane = t & 63, wd = t >> 6;
  #pragma unroll
  for (int off = 1; off < 64; off <<= 1) {
    const int u = __shfl_up(v, off);
    if (lane >= off) v += u;
  }
  __shared__ int wsum[4];
  if (lane == 63) wsum[wd] = v;
  __syncthreads();
  int wb = 0;
  #pragma unroll
  for (int k = 0; k < 3; ++k)
    if (k < wd) wb += wsum[k];
  int e = wb + v - s;  // exclusive prefix at this thread's first item
  const int base = b * 1024 + t * 4;
  posx[base + 0] = e;
  if (f0) midxg[b * 1024 + e] = t * 4 + 0;
  e += f0;
  posx[base + 1] = e;
  if (f1) midxg[b * 1024 + e] = t * 4 + 1;
  e += f1;
  posx[base + 2] = e;
  if (f2) midxg[b * 1024 + e] = t * 4 + 2;
  e += f2;
  posx[base + 3] = e;
  if (f3) midxg[b * 1024 + e] = t * 4 + 3;
  e += f3;
  if (t == 255) cntA[b] = e;
}

__global__ void offsets_k(const int* __restrict__ cntA, int* __restrict__ off17) {
  if (threadIdx.x == 0) {
    int a = 0;
    off17[0] = 0;
    for (int b = 0; b < 16; ++b) { a += cntA[b]; off17[b + 1] = a; }
  }
}

// -- y -> Yh [b,m,h] fp16 (full) AND Ytc [b,h,jcompact] fp16 (masked-compact) --
__global__ __launch_bounds__(256) void transpose_y(const float* __restrict__ Y,
                                                   const int* __restrict__ mask,
                                                   const int* __restrict__ posx,
                                                   const int* __restrict__ cntA,
                                                   f16* __restrict__ Yh,
                                                   f16* __restrict__ Ytc) {
  __shared__ f16 tile[64][36];
  __shared__ int jcol[32];
  __shared__ int jval[32];
  const int b = blockIdx.z;
  const float* Yb = Y + (long)b * L * H;
  f16* Yhb = Yh + (long)b * L * H;
  f16* Ytb = Ytc + (long)b * L * H;
  const int h0 = blockIdx.x * 64, m0 = blockIdx.y * 32;
  const int tid = threadIdx.x;

  if (tid < 32) {
    jcol[tid] = posx[b * 1024 + m0 + tid];
    jval[tid] = (mask[b * 1024 + m0 + tid] == 0);
  }
  const int hc = (tid & 15) * 4;
  #pragma unroll
  for (int rr = 0; rr < 2; ++rr) {
    const int m = (tid >> 4) + rr * 16;
    const float4 v = *(const float4*)(&Yb[(long)(m0 + m) * H + h0 + hc]);
    half4 h4;
    h4[0] = (f16)v.x; h4[1] = (f16)v.y; h4[2] = (f16)v.z; h4[3] = (f16)v.w;
    *(half4*)(&Yhb[(long)(m0 + m) * H + h0 + hc]) = h4;
    tile[hc + 0][m] = h4[0];
    tile[hc + 1][m] = h4[1];
    tile[hc + 2][m] = h4[2];
    tile[hc + 3][m] = h4[3];
  }
  __syncthreads();
  const int hh = tid >> 2;        // 0..63
  const int mg = (tid & 3) * 8;   // m octet
  #pragma unroll
  for (int i = 0; i < 8; ++i) {
    const int m = mg + i;
    if (jval[m])
      Ytb[(long)(h0 + hh) * L + jcol[m]] = tile[hh][m];
  }
  if (m0 == L - 32) {  // zero-fill pad cols [cnt, ceil32(cnt))
    const int cnt = cntA[b];
    const int jend = (cnt + 31) & ~31;
    const int jz = cnt + (tid & 31);
    if (jz < jend)
      for (int r = tid >> 5; r < 64; r += 8)
        Ytb[(long)(h0 + r) * L + jz] = (f16)0.f;
  }
}

// =====================================================================
// 256x128 tile GEMM (R5-proven schedule, untouched inner loop).
// MODE 0: proj  C[r,1024]=relu(Agather[r,:]@Wh^T+b) fp16; rows gathered
//         from x ++ unmasked-y; early-exit past 16384+total.
// MODE 1: scores Sc[b][l,j]=Xp[l,:]@Ypc[j,:]^T f32; col-exit at cnt32.
// MODE 2: PV    out[b][l,h]=Alpha[l,:cnt32]@Ytc[h,:cnt32]^T f32;
//         runtime NT=cnt32/32.
// =====================================================================
#define GLD16(g, l)                                           \
  __builtin_amdgcn_global_load_lds(                           \
      (const __attribute__((address_space(1))) void*)(g),     \
      (__attribute__((address_space(3))) void*)(l), 16, 0, 0)

__device__ __forceinline__ long gather_row(int r, const int* __restrict__ o17,
                                           const int* __restrict__ midxg,
                                           int total) {
  if (r < 16384) return r;
  int g = r - 16384;
  if (g >= total) g = total - 1;
  int b = 0;
  #pragma unroll
  for (int k = 1; k <= 16; ++k) b += (g >= o17[k]);
  const int m = midxg[b * 1024 + g - o17[b]];
  return 16384L + b * 1024 + m;
}

template <int MODE>
__global__ __launch_bounds__(512, 4) void gemm128(
    const f16* __restrict__ Ap, const f16* __restrict__ Bp,
    const float* __restrict__ bias, void* __restrict__ Cp,
    const int* __restrict__ off17, const int* __restrict__ midxg,
    int nxyShift) {
  __shared__ f16 lds[3 * 12288];  // 3 slots x (A 16KB + B 8KB) = 72 KB
  constexpr int N = 1024, K = 1024;

  const int tid = threadIdx.x;
  const int lane = tid & 63;
  const int wid = tid >> 6;
  const int wm = wid >> 1;
  const int wn = wid & 1;

  const int nwg = gridDim.x;
  const int orig = blockIdx.x;
  const int wg = (orig & 7) * (nwg >> 3) + (orig >> 3);
  const int bz = wg >> nxyShift;
  const int rxy = wg & ((1 << nxyShift) - 1);
  const int bx = rxy & 7;
  const int by = rxy >> 3;
  const int row0 = by * 256, col0 = bx * 128;

  const int srow = lane >> 2;
  const int sslot = (lane & 3) ^ ((lane >> 3) & 3);

  int nt = 32;
  const f16 *gA0, *gA1, *gB0;
  if (MODE == 0) {
    const int total = off17[16];
    if (row0 >= 16384 + total) return;
    gA0 = Ap + gather_row(row0 + wid * 32 + srow, off17, midxg, total) * K +
          sslot * 8;
    gA1 = Ap + gather_row(row0 + wid * 32 + 16 + srow, off17, midxg, total) * K +
          sslot * 8;
    gB0 = Bp + (long)(col0 + wid * 16 + srow) * K + sslot * 8;
  } else if (MODE == 1) {
    const int cnt = off17[bz + 1] - off17[bz];
    if (col0 >= ((cnt + 31) & ~31)) return;
    gA0 = Ap + (long)(bz * 1024 + row0 + wid * 32 + srow) * K + sslot * 8;
    gA1 = gA0 + 16L * K;
    gB0 = Ap + (long)(16384 + off17[bz] + col0 + wid * 16 + srow) * K +
          sslot * 8;
  } else {
    const int cnt = off17[bz + 1] - off17[bz];
    nt = ((cnt + 31) & ~31) >> 5;
    gA0 = Ap + (long)bz * (1 << 20) +
          (long)(row0 + wid * 32 + srow) * 1024 + sslot * 8;
    gA1 = gA0 + 16L * 1024;
    gB0 = Bp + (long)bz * (1 << 20) +
          (long)(col0 + wid * 16 + srow) * 1024 + sslot * 8;
  }
  char* ldsw = (char*)lds;

  const int fr = lane & 15, fq = lane >> 4;
  const int rsw = (fq ^ ((fr >> 1) & 3)) << 4;
  const int aByte = (wm * 64 + fr) * 64 + rsw;
  const int bByte = (wn * 64 + fr) * 64 + rsw;
  const char* ldsr = (const char*)lds;

  f32x4 acc[4][4];
  #pragma unroll
  for (int i = 0; i < 4; ++i)
    #pragma unroll
    for (int j = 0; j < 4; ++j)
      acc[i][j] = (f32x4){0.f, 0.f, 0.f, 0.f};

  #pragma unroll
  for (int p = 0; p < 2; ++p) {
    char* sb = ldsw + p * 24576;
    GLD16(gA0, sb + wid * 2048);
    GLD16(gA1, sb + wid * 2048 + 1024);
    GLD16(gB0, sb + 16384 + wid * 1024);
    gA0 += 32; gA1 += 32; gB0 += 32;
  }
  asm volatile("s_waitcnt vmcnt(3)" ::: "memory");
  __builtin_amdgcn_s_barrier();
  __builtin_amdgcn_sched_barrier(0);

  int cb = 0, pb = 2 * 24576;
  const int NT = (MODE == 2) ? nt : 32;
  for (int t = 0; t < NT; ++t) {
    if (t + 2 < NT) {
      char* sb = ldsw + pb;
      GLD16(gA0, sb + wid * 2048);
      GLD16(gA1, sb + wid * 2048 + 1024);
      GLD16(gB0, sb + 16384 + wid * 1024);
      gA0 += 32; gA1 += 32; gB0 += 32;
    }
    const char* base = ldsr + cb;
    half8 av[4], bv[4];
    #pragma unroll
    for (int j = 0; j < 4; ++j)
      bv[j] = *(const half8*)(base + 16384 + bByte + j * 1024);
    #pragma unroll
    for (int i = 0; i < 4; ++i)
      av[i] = *(const half8*)(base + aByte + i * 1024);
    __builtin_amdgcn_s_setprio(1);
    #pragma unroll
    for (int i = 0; i < 4; ++i)
      #pragma unroll
      for (int j = 0; j < 4; ++j)
        acc[i][j] = __builtin_amdgcn_mfma_f32_16x16x32_f16(av[i], bv[j],
                                                           acc[i][j], 0, 0, 0);
    __builtin_amdgcn_s_setprio(0);
    if (t < NT - 1) {
      __builtin_amdgcn_sched_barrier(0);
      if (t <= NT - 3)
        asm volatile("s_waitcnt vmcnt(3)" ::: "memory");
      else
        asm volatile("s_waitcnt vmcnt(0)" ::: "memory");
      __builtin_amdgcn_s_barrier();
      __builtin_amdgcn_sched_barrier(0);
      cb = (cb == 49152) ? 0 : cb + 24576;
      pb = (pb == 49152) ? 0 : pb + 24576;
    }
  }

  if (MODE == 0) {
    f16* C = (f16*)Cp;
    #pragma unroll
    for (int j = 0; j < 4; ++j) {
      const int col = col0 + wn * 64 + j * 16 + fr;
      const float bvs = bias[col];
      #pragma unroll
      for (int i = 0; i < 4; ++i) {
        const int rowb = row0 + wm * 64 + i * 16 + fq * 4;
        #pragma unroll
        for (int r = 0; r < 4; ++r) {
          float v = acc[i][j][r] + bvs;
          v = v > 0.f ? v : 0.f;
          C[(long)(rowb + r) * N + col] = (f16)v;
        }
      }
    }
  } else {
    float* C = (float*)Cp + (long)bz * (1 << 20);
    #pragma unroll
    for (int j = 0; j < 4; ++j) {
      const int col = col0 + wn * 64 + j * 16 + fr;
      #pragma unroll
      for (int i = 0; i < 4; ++i) {
        const int rowb = row0 + wm * 64 + i * 16 + fq * 4;
        #pragma unroll
        for (int r = 0; r < 4; ++r)
          C[(long)(rowb + r) * N + col] = acc[i][j][r];
      }
    }
  }
}

// ------- masked-compact row softmax: Sc f32 [b][l][j<cnt] -> alpha fp16 -------
__global__ __launch_bounds__(256) void softmax_rows(const float* __restrict__ S,
                                                    const int* __restrict__ off17,
                                                    f16* __restrict__ P) {
  const int b = blockIdx.y;
  const int l = blockIdx.x;
  const int t = threadIdx.x;
  const int cnt = off17[b + 1] - off17[b];
  const int cnt32 = (cnt + 31) & ~31;
  const float* srow = S + ((long)b * L + l) * L;
  f16* prow = P + ((long)b * L + l) * L;

  const float4 v = *(const float4*)(&srow[t * 4]);
  const int j0 = t * 4;
  const float x0 = (j0 + 0 < cnt) ? v.x : -1e30f;
  const float x1 = (j0 + 1 < cnt) ? v.y : -1e30f;
  const float x2 = (j0 + 2 < cnt) ? v.z : -1e30f;
  const float x3 = (j0 + 3 < cnt) ? v.w : -1e30f;

  float mx = fmaxf(fmaxf(x0, x1), fmaxf(x2, x3));
  #pragma unroll
  for (int off = 32; off >= 1; off >>= 1)
    mx = fmaxf(mx, __shfl_xor(mx, off));
  __shared__ float red[8];
  const int wd = t >> 6, lane = t & 63;
  if (lane == 0) red[wd] = mx;
  __syncthreads();
  mx = fmaxf(fmaxf(red[0], red[1]), fmaxf(red[2], red[3]));

  const float e0 = __expf(x0 - mx), e1 = __expf(x1 - mx);
  const float e2 = __expf(x2 - mx), e3 = __expf(x3 - mx);
  float s = e0 + e1 + e2 + e3;
  #pragma unroll
  for (int off = 32; off >= 1; off >>= 1)
    s += __shfl_xor(s, off);
  if (lane == 0) red[4 + wd] = s;
  __syncthreads();
  s = red[4] + red[5] + red[6] + red[7];
  const float inv = 1.f / s;
  if (j0 < cnt32) {
    half4 h;
    h[0] = (f16)(e0 * inv); h[1] = (f16)(e1 * inv);
    h[2] = (f16)(e2 * inv); h[3] = (f16)(e3 * inv);
    *(half4*)(&prow[j0]) = h;
  }
}

extern "C" void kernel_launch(void* const* d_in, const int* in_sizes, int n_in,
                              void* d_out, int out_size, void* d_ws,
                              size_t ws_size, hipStream_t stream) {
  const float* x = (const float*)d_in[0];
  const float* y = (const float*)d_in[1];
  const int* ymask = (const int*)d_in[2];
  const float* W = (const float*)d_in[3];
  const float* bias = (const float*)d_in[4];
  float* out = (float*)d_out;

  // ws: Wh 2MB | Ytc 32MB | XYp 64MB (meta in tail) | XYh 64MB (Sc alias)
  char* ws = (char*)d_ws;
  f16* Wh = (f16*)(ws);
  f16* Ytc = (f16*)(ws + (1L << 21));
  f16* XYp = (f16*)(ws + (1L << 21) + (1L << 25));
  f16* XYh = (f16*)(ws + (1L << 21) + (1L << 25) + (1L << 26));
  float* Sc = (float*)XYh;  // XYh dead after proj
  f16* Alpha = XYp;         // Xp rows dead after scores

  // meta in XYp tail (rows >= 30720 never touched by proj/scores/alpha)
  char* meta = (char*)XYp + 60L * (1 << 20);
  int* posx = (int*)meta;                  // 64 KB
  int* midxg = (int*)(meta + (1 << 16));   // 64 KB
  int* cntA = (int*)(meta + (1 << 17));    // 64 B
  int* off17 = (int*)(meta + (1 << 17) + 256);

  f16* Xh = XYh;
  f16* Yh = XYh + (long)BATCH * L * H;

  cvt_wx<<<512 + 8192, 256, 0, stream>>>(W, Wh, x, Xh);
  mask_scan<<<16, 256, 0, stream>>>(ymask, posx, midxg, cntA);
  offsets_k<<<1, 64, 0, stream>>>(cntA, off17);
  transpose_y<<<dim3(16, 32, BATCH), 256, 0, stream>>>(y, ymask, posx, cntA,
                                                       Yh, Ytc);

  // proj (gathered rows): XYp[r] = relu(XYh[gather(r)] @ Wh^T + b)
  gemm128<0><<<1024, 512, 0, stream>>>(XYh, Wh, bias, XYp, off17, midxg, 10);

  // scores: Sc[b][l][j] = Xp[l] . Ypc[j]
  gemm128<1><<<512, 512, 0, stream>>>(XYp, nullptr, nullptr, Sc, off17, midxg,
                                      5);

  // alpha = softmax over j<cnt
  softmax_rows<<<dim3(L, BATCH), 256, 0, stream>>>(Sc, off17, Alpha);

  // out[b][l][h] = sum_j alpha[l][j] * Ytc[h][j]
  gemm128<2><<<512, 512, 0, stream>>>(Alpha, Ytc, nullptr, out, off17, midxg,
                                      5);
}

// Round 9
// 201.834 us; speedup vs baseline: 1.2160x; 1.0906x over previous
//
#include <hip/hip_runtime.h>
#include <hip/hip_fp16.h>

typedef _Float16 f16;
typedef _Float16 half4 __attribute__((ext_vector_type(4)));
typedef _Float16 half8 __attribute__((ext_vector_type(8)));
typedef float f32x4 __attribute__((ext_vector_type(4)));

#define BATCH 16
#define L 1024
#define H 1024

// -------- f32 -> fp16 bulk convert: W (blocks [0,512)) + x (rest) --------
__global__ __launch_bounds__(256) void cvt_wx(const float* __restrict__ W,
                                              f16* __restrict__ Wh,
                                              const float* __restrict__ x,
                                              f16* __restrict__ Xh) {
  const float* src;
  f16* dst;
  long i;
  if (blockIdx.x < 512) {
    src = W; dst = Wh;
    i = (long)blockIdx.x * 2048 + threadIdx.x * 8;
  } else {
    src = x; dst = Xh;
    i = ((long)blockIdx.x - 512) * 2048 + threadIdx.x * 8;
  }
  const float4 a = *(const float4*)(&src[i]);
  const float4 b = *(const float4*)(&src[i + 4]);
  half8 h;
  h[0] = (f16)a.x; h[1] = (f16)a.y; h[2] = (f16)a.z; h[3] = (f16)a.w;
  h[4] = (f16)b.x; h[5] = (f16)b.y; h[6] = (f16)b.z; h[7] = (f16)b.w;
  *(half8*)(&dst[i]) = h;
}

// ---- per-batch mask prefix scan: posx (exclusive), cnt ----
__global__ __launch_bounds__(256) void mask_scan(const int* __restrict__ mask,
                                                 int* __restrict__ posx,
                                                 int* __restrict__ cntA) {
  const int b = blockIdx.x;
  const int t = threadIdx.x;
  const int4 mk = *(const int4*)(&mask[b * 1024 + t * 4]);
  const int f0 = (mk.x == 0), f1 = (mk.y == 0);
  const int f2 = (mk.z == 0), f3 = (mk.w == 0);
  const int s = f0 + f1 + f2 + f3;
  int v = s;
  const int lane = t & 63, wd = t >> 6;
  #pragma unroll
  for (int off = 1; off < 64; off <<= 1) {
    const int u = __shfl_up(v, off);
    if (lane >= off) v += u;
  }
  __shared__ int wsum[4];
  if (lane == 63) wsum[wd] = v;
  __syncthreads();
  int wb = 0;
  #pragma unroll
  for (int k = 0; k < 3; ++k)
    if (k < wd) wb += wsum[k];
  int e = wb + v - s;
  const int base = b * 1024 + t * 4;
  posx[base + 0] = e; e += f0;
  posx[base + 1] = e; e += f1;
  posx[base + 2] = e; e += f2;
  posx[base + 3] = e; e += f3;
  if (t == 255) cntA[b] = e;
}

__global__ void offsets_k(const int* __restrict__ cntA, int* __restrict__ off17) {
  if (threadIdx.x == 0) {
    int a = 0;
    off17[0] = 0;
    for (int b = 0; b < 16; ++b) { a += cntA[b]; off17[b + 1] = a; }
  }
}

// -- y [b,m,h] f32 -> Yhc (compact fp16 rows, coalesced) + Ytc (compact
//    transposed [b,h,j], contiguous col writes; pad cols zeroed) --
__global__ __launch_bounds__(256) void transpose_y(
    const float* __restrict__ Y, const int* __restrict__ mask,
    const int* __restrict__ posx, const int* __restrict__ cntA,
    const int* __restrict__ off17, f16* __restrict__ Yhc,
    f16* __restrict__ Ytc) {
  __shared__ f16 tile[64][36];
  __shared__ int cmap[32];
  const int b = blockIdx.z;
  const int h0 = blockIdx.x * 64, m0 = blockIdx.y * 32;
  const int tid = threadIdx.x;
  const float* Yb = Y + (long)b * L * H;
  f16* Ytb = Ytc + (long)b * L * H;

  const int jbase = posx[b * 1024 + m0];
  const int cnt = cntA[b];
  const int nloc = ((m0 == L - 32) ? cnt : posx[b * 1024 + m0 + 32]) - jbase;
  const int rowbase = off17[b];

  const int hc = (tid & 15) * 4;
  #pragma unroll
  for (int rr = 0; rr < 2; ++rr) {
    const int m = (tid >> 4) + rr * 16;
    const int gm = b * 1024 + m0 + m;
    const int jc = posx[gm];
    const int un = (mask[gm] == 0);
    const float4 v = *(const float4*)(&Yb[(long)(m0 + m) * H + h0 + hc]);
    half4 h4;
    h4[0] = (f16)v.x; h4[1] = (f16)v.y; h4[2] = (f16)v.z; h4[3] = (f16)v.w;
    tile[hc + 0][m] = h4[0];
    tile[hc + 1][m] = h4[1];
    tile[hc + 2][m] = h4[2];
    tile[hc + 3][m] = h4[3];
    if (un) {
      *(half4*)(&Yhc[(long)(rowbase + jc) * H + h0 + hc]) = h4;
      if (hc == 0) cmap[jc - jbase] = m;
    }
  }
  __syncthreads();
  // Ytc write: cols [jbase, jbase+nloc), contiguous per row
  {
    const int c = tid & 31;
    if (c < nloc) {
      const int m = cmap[c];
      for (int hh = tid >> 5; hh < 64; hh += 8)
        Ytb[(long)(h0 + hh) * L + jbase + c] = tile[hh][m];
    }
  }
  // pad-zero cols [cnt, cnt32)
  if (m0 == L - 32) {
    const int p = ((cnt + 31) & ~31) - cnt;
    const int c = tid & 31;
    if (c < p)
      for (int hh = tid >> 5; hh < 64; hh += 8)
        Ytb[(long)(h0 + hh) * L + cnt + c] = (f16)0.f;
  }
}

// =====================================================================
// 256x128 tile GEMM (R5-proven schedule, untouched inner loop).
// MODE 0: proj  C[r,1024]=relu(A[r,:]@Wh^T+b) fp16 over contiguous
//         compact rows [Xh ++ Yhc]; tile early-exit past 16384+total+32.
// MODE 1: scores Sc[b][l,j]=Xp[l,:]@Ypc[j,:]^T f32; col-exit at cnt32.
// MODE 2: PV    out[b][l,h]=Alpha[l,:cnt32]@Ytc[h,:cnt32]^T f32;
//         runtime NT=cnt32/32.
// =====================================================================
#define GLD16(g, l)                                           \
  __builtin_amdgcn_global_load_lds(                           \
      (const __attribute__((address_space(1))) void*)(g),     \
      (__attribute__((address_space(3))) void*)(l), 16, 0, 0)

template <int MODE>
__global__ __launch_bounds__(512, 4) void gemm128(
    const f16* __restrict__ Ap, const f16* __restrict__ Bp,
    const float* __restrict__ bias, void* __restrict__ Cp,
    const int* __restrict__ off17, int nxyShift) {
  __shared__ f16 lds[3 * 12288];  // 3 slots x (A 16KB + B 8KB) = 72 KB
  constexpr int N = 1024, K = 1024;

  const int tid = threadIdx.x;
  const int lane = tid & 63;
  const int wid = tid >> 6;
  const int wm = wid >> 1;
  const int wn = wid & 1;

  const int nwg = gridDim.x;
  const int orig = blockIdx.x;
  const int wg = (orig & 7) * (nwg >> 3) + (orig >> 3);
  const int bz = wg >> nxyShift;
  const int rxy = wg & ((1 << nxyShift) - 1);
  const int bx = rxy & 7;
  const int by = rxy >> 3;
  const int row0 = by * 256, col0 = bx * 128;

  const int srow = lane >> 2;
  const int sslot = (lane & 3) ^ ((lane >> 3) & 3);

  int nt = 32;
  const f16 *gA0, *gA1, *gB0;
  if (MODE == 0) {
    const int total = off17[16];
    if (row0 >= 16384 + total + 32) return;
    gA0 = Ap + (long)(row0 + wid * 32 + srow) * K + sslot * 8;
    gA1 = gA0 + 16L * K;
    gB0 = Bp + (long)(col0 + wid * 16 + srow) * K + sslot * 8;
  } else if (MODE == 1) {
    const int cnt = off17[bz + 1] - off17[bz];
    if (col0 >= ((cnt + 31) & ~31)) return;
    gA0 = Ap + (long)(bz * 1024 + row0 + wid * 32 + srow) * K + sslot * 8;
    gA1 = gA0 + 16L * K;
    gB0 = Ap + (long)(16384 + off17[bz] + col0 + wid * 16 + srow) * K +
          sslot * 8;
  } else {
    const int cnt = off17[bz + 1] - off17[bz];
    nt = ((cnt + 31) & ~31) >> 5;
    gA0 = Ap + (long)bz * (1 << 20) +
          (long)(row0 + wid * 32 + srow) * 1024 + sslot * 8;
    gA1 = gA0 + 16L * 1024;
    gB0 = Bp + (long)bz * (1 << 20) +
          (long)(col0 + wid * 16 + srow) * 1024 + sslot * 8;
  }
  char* ldsw = (char*)lds;

  const int fr = lane & 15, fq = lane >> 4;
  const int rsw = (fq ^ ((fr >> 1) & 3)) << 4;
  const int aByte = (wm * 64 + fr) * 64 + rsw;
  const int bByte = (wn * 64 + fr) * 64 + rsw;
  const char* ldsr = (const char*)lds;

  f32x4 acc[4][4];
  #pragma unroll
  for (int i = 0; i < 4; ++i)
    #pragma unroll
    for (int j = 0; j < 4; ++j)
      acc[i][j] = (f32x4){0.f, 0.f, 0.f, 0.f};

  #pragma unroll
  for (int p = 0; p < 2; ++p) {
    char* sb = ldsw + p * 24576;
    GLD16(gA0, sb + wid * 2048);
    GLD16(gA1, sb + wid * 2048 + 1024);
    GLD16(gB0, sb + 16384 + wid * 1024);
    gA0 += 32; gA1 += 32; gB0 += 32;
  }
  asm volatile("s_waitcnt vmcnt(3)" ::: "memory");
  __builtin_amdgcn_s_barrier();
  __builtin_amdgcn_sched_barrier(0);

  int cb = 0, pb = 2 * 24576;
  const int NT = (MODE == 2) ? nt : 32;
  for (int t = 0; t < NT; ++t) {
    if (t + 2 < NT) {
      char* sb = ldsw + pb;
      GLD16(gA0, sb + wid * 2048);
      GLD16(gA1, sb + wid * 2048 + 1024);
      GLD16(gB0, sb + 16384 + wid * 1024);
      gA0 += 32; gA1 += 32; gB0 += 32;
    }
    const char* base = ldsr + cb;
    half8 av[4], bv[4];
    #pragma unroll
    for (int j = 0; j < 4; ++j)
      bv[j] = *(const half8*)(base + 16384 + bByte + j * 1024);
    #pragma unroll
    for (int i = 0; i < 4; ++i)
      av[i] = *(const half8*)(base + aByte + i * 1024);
    __builtin_amdgcn_s_setprio(1);
    #pragma unroll
    for (int i = 0; i < 4; ++i)
      #pragma unroll
      for (int j = 0; j < 4; ++j)
        acc[i][j] = __builtin_amdgcn_mfma_f32_16x16x32_f16(av[i], bv[j],
                                                           acc[i][j], 0, 0, 0);
    __builtin_amdgcn_s_setprio(0);
    if (t < NT - 1) {
      __builtin_amdgcn_sched_barrier(0);
      if (t <= NT - 3)
        asm volatile("s_waitcnt vmcnt(3)" ::: "memory");
      else
        asm volatile("s_waitcnt vmcnt(0)" ::: "memory");
      __builtin_amdgcn_s_barrier();
      __builtin_amdgcn_sched_barrier(0);
      cb = (cb == 49152) ? 0 : cb + 24576;
      pb = (pb == 49152) ? 0 : pb + 24576;
    }
  }

  if (MODE == 0) {
    f16* C = (f16*)Cp;
    #pragma unroll
    for (int j = 0; j < 4; ++j) {
      const int col = col0 + wn * 64 + j * 16 + fr;
      const float bvs = bias[col];
      #pragma unroll
      for (int i = 0; i < 4; ++i) {
        const int rowb = row0 + wm * 64 + i * 16 + fq * 4;
        #pragma unroll
        for (int r = 0; r < 4; ++r) {
          float v = acc[i][j][r] + bvs;
          v = v > 0.f ? v : 0.f;
          C[(long)(rowb + r) * N + col] = (f16)v;
        }
      }
    }
  } else {
    float* C = (float*)Cp + (long)bz * (1 << 20);
    #pragma unroll
    for (int j = 0; j < 4; ++j) {
      const int col = col0 + wn * 64 + j * 16 + fr;
      #pragma unroll
      for (int i = 0; i < 4; ++i) {
        const int rowb = row0 + wm * 64 + i * 16 + fq * 4;
        #pragma unroll
        for (int r = 0; r < 4; ++r)
          C[(long)(rowb + r) * N + col] = acc[i][j][r];
      }
    }
  }
}

// ------- masked-compact row softmax: Sc f32 [b][l][j<cnt] -> alpha fp16 -------
__global__ __launch_bounds__(256) void softmax_rows(const float* __restrict__ S,
                                                    const int* __restrict__ off17,
                                                    f16* __restrict__ P) {
  const int b = blockIdx.y;
  const int l = blockIdx.x;
  const int t = threadIdx.x;
  const int cnt = off17[b + 1] - off17[b];
  const int cnt32 = (cnt + 31) & ~31;
  const float* srow = S + ((long)b * L + l) * L;
  f16* prow = P + ((long)b * L + l) * L;

  const float4 v = *(const float4*)(&srow[t * 4]);
  const int j0 = t * 4;
  const float x0 = (j0 + 0 < cnt) ? v.x : -1e30f;
  const float x1 = (j0 + 1 < cnt) ? v.y : -1e30f;
  const float x2 = (j0 + 2 < cnt) ? v.z : -1e30f;
  const float x3 = (j0 + 3 < cnt) ? v.w : -1e30f;

  float mx = fmaxf(fmaxf(x0, x1), fmaxf(x2, x3));
  #pragma unroll
  for (int off = 32; off >= 1; off >>= 1)
    mx = fmaxf(mx, __shfl_xor(mx, off));
  __shared__ float red[8];
  const int wd = t >> 6, lane = t & 63;
  if (lane == 0) red[wd] = mx;
  __syncthreads();
  mx = fmaxf(fmaxf(red[0], red[1]), fmaxf(red[2], red[3]));

  const float e0 = __expf(x0 - mx), e1 = __expf(x1 - mx);
  const float e2 = __expf(x2 - mx), e3 = __expf(x3 - mx);
  float s = e0 + e1 + e2 + e3;
  #pragma unroll
  for (int off = 32; off >= 1; off >>= 1)
    s += __shfl_xor(s, off);
  if (lane == 0) red[4 + wd] = s;
  __syncthreads();
  s = red[4] + red[5] + red[6] + red[7];
  const float inv = 1.f / s;
  if (j0 < cnt32) {
    half4 h;
    h[0] = (f16)(e0 * inv); h[1] = (f16)(e1 * inv);
    h[2] = (f16)(e2 * inv); h[3] = (f16)(e3 * inv);
    *(half4*)(&prow[j0]) = h;
  }
}

extern "C" void kernel_launch(void* const* d_in, const int* in_sizes, int n_in,
                              void* d_out, int out_size, void* d_ws,
                              size_t ws_size, hipStream_t stream) {
  const float* x = (const float*)d_in[0];
  const float* y = (const float*)d_in[1];
  const int* ymask = (const int*)d_in[2];
  const float* W = (const float*)d_in[3];
  const float* bias = (const float*)d_in[4];
  float* out = (float*)d_out;

  // ws: Wh 2MB | Ytc 32MB | XYp 64MB (meta in tail) | XYh 64MB (Sc alias)
  char* ws = (char*)d_ws;
  f16* Wh = (f16*)(ws);
  f16* Ytc = (f16*)(ws + (1L << 21));
  f16* XYp = (f16*)(ws + (1L << 21) + (1L << 25));
  f16* XYh = (f16*)(ws + (1L << 21) + (1L << 25) + (1L << 26));
  float* Sc = (float*)XYh;  // XYh dead after proj
  f16* Alpha = XYp;         // Xp rows dead after scores

  // meta in XYp tail (rows >= 30720 never touched by proj/scores/alpha)
  char* meta = (char*)XYp + 60L * (1 << 20);
  int* posx = (int*)meta;                  // 64 KB
  int* cntA = (int*)(meta + (1 << 16));    // 64 B
  int* off17 = (int*)(meta + (1 << 16) + 256);

  f16* Xh = XYh;
  f16* Yhc = XYh + (long)BATCH * L * H;  // compact y rows

  cvt_wx<<<512 + 8192, 256, 0, stream>>>(W, Wh, x, Xh);
  mask_scan<<<16, 256, 0, stream>>>(ymask, posx, cntA);
  offsets_k<<<1, 64, 0, stream>>>(cntA, off17);
  transpose_y<<<dim3(16, 32, BATCH), 256, 0, stream>>>(y, ymask, posx, cntA,
                                                       off17, Yhc, Ytc);

  // proj: XYp[r] = relu(XYh[r] @ Wh^T + b), compact contiguous rows
  gemm128<0><<<1024, 512, 0, stream>>>(XYh, Wh, bias, XYp, off17, 10);

  // scores: Sc[b][l][j] = Xp[l] . Ypc[j]
  gemm128<1><<<512, 512, 0, stream>>>(XYp, nullptr, nullptr, Sc, off17, 5);

  // alpha = softmax over j<cnt
  softmax_rows<<<dim3(L, BATCH), 256, 0, stream>>>(Sc, off17, Alpha);

  // out[b][l][h] = sum_j alpha[l][j] * Ytc[h][j]
  gemm128<2><<<512, 512, 0, stream>>>(Alpha, Ytc, nullptr, out, off17, 5);
}

// Round 10
// 199.627 us; speedup vs baseline: 1.2294x; 1.0111x over previous
//
#include <hip/hip_runtime.h>
#include <hip/hip_fp16.h>

typedef _Float16 f16;
typedef _Float16 half4 __attribute__((ext_vector_type(4)));
typedef _Float16 half8 __attribute__((ext_vector_type(8)));
typedef float f32x4 __attribute__((ext_vector_type(4)));

#define BATCH 16
#define L 1024
#define H 1024

// -------- f32 -> fp16 bulk convert: W (blocks [0,512)) + x (rest) --------
__global__ __launch_bounds__(256) void cvt_wx(const float* __restrict__ W,
                                              f16* __restrict__ Wh,
                                              const float* __restrict__ x,
                                              f16* __restrict__ Xh) {
  const float* src;
  f16* dst;
  long i;
  if (blockIdx.x < 512) {
    src = W; dst = Wh;
    i = (long)blockIdx.x * 2048 + threadIdx.x * 8;
  } else {
    src = x; dst = Xh;
    i = ((long)blockIdx.x - 512) * 2048 + threadIdx.x * 8;
  }
  const float4 a = *(const float4*)(&src[i]);
  const float4 b = *(const float4*)(&src[i + 4]);
  half8 h;
  h[0] = (f16)a.x; h[1] = (f16)a.y; h[2] = (f16)a.z; h[3] = (f16)a.w;
  h[4] = (f16)b.x; h[5] = (f16)b.y; h[6] = (f16)b.z; h[7] = (f16)b.w;
  *(half8*)(&dst[i]) = h;
}

// ---- per-batch mask prefix scan: posx (exclusive), cnt ----
__global__ __launch_bounds__(256) void mask_scan(const int* __restrict__ mask,
                                                 int* __restrict__ posx,
                                                 int* __restrict__ cntA) {
  const int b = blockIdx.x;
  const int t = threadIdx.x;
  const int4 mk = *(const int4*)(&mask[b * 1024 + t * 4]);
  const int f0 = (mk.x == 0), f1 = (mk.y == 0);
  const int f2 = (mk.z == 0), f3 = (mk.w == 0);
  const int s = f0 + f1 + f2 + f3;
  int v = s;
  const int lane = t & 63, wd = t >> 6;
  #pragma unroll
  for (int off = 1; off < 64; off <<= 1) {
    const int u = __shfl_up(v, off);
    if (lane >= off) v += u;
  }
  __shared__ int wsum[4];
  if (lane == 63) wsum[wd] = v;
  __syncthreads();
  int wb = 0;
  #pragma unroll
  for (int k = 0; k < 3; ++k)
    if (k < wd) wb += wsum[k];
  int e = wb + v - s;
  const int base = b * 1024 + t * 4;
  posx[base + 0] = e; e += f0;
  posx[base + 1] = e; e += f1;
  posx[base + 2] = e; e += f2;
  posx[base + 3] = e; e += f3;
  if (t == 255) cntA[b] = e;
}

__global__ void offsets_k(const int* __restrict__ cntA, int* __restrict__ off17) {
  if (threadIdx.x == 0) {
    int a = 0;
    off17[0] = 0;
    for (int b = 0; b < 16; ++b) { a += cntA[b]; off17[b + 1] = a; }
  }
}

// -- y [b,m,h] f32 -> Yhc (compact fp16 rows, coalesced) + Ytc (compact
//    transposed [b,h,j], contiguous col writes; pad cols zeroed) --
__global__ __launch_bounds__(256) void transpose_y(
    const float* __restrict__ Y, const int* __restrict__ mask,
    const int* __restrict__ posx, const int* __restrict__ cntA,
    const int* __restrict__ off17, f16* __restrict__ Yhc,
    f16* __restrict__ Ytc) {
  __shared__ f16 tile[64][36];
  __shared__ int cmap[32];
  const int b = blockIdx.z;
  const int h0 = blockIdx.x * 64, m0 = blockIdx.y * 32;
  const int tid = threadIdx.x;
  const float* Yb = Y + (long)b * L * H;
  f16* Ytb = Ytc + (long)b * L * H;

  const int jbase = posx[b * 1024 + m0];
  const int cnt = cntA[b];
  const int nloc = ((m0 == L - 32) ? cnt : posx[b * 1024 + m0 + 32]) - jbase;
  const int rowbase = off17[b];

  const int hc = (tid & 15) * 4;
  #pragma unroll
  for (int rr = 0; rr < 2; ++rr) {
    const int m = (tid >> 4) + rr * 16;
    const int gm = b * 1024 + m0 + m;
    const int jc = posx[gm];
    const int un = (mask[gm] == 0);
    const float4 v = *(const float4*)(&Yb[(long)(m0 + m) * H + h0 + hc]);
    half4 h4;
    h4[0] = (f16)v.x; h4[1] = (f16)v.y; h4[2] = (f16)v.z; h4[3] = (f16)v.w;
    tile[hc + 0][m] = h4[0];
    tile[hc + 1][m] = h4[1];
    tile[hc + 2][m] = h4[2];
    tile[hc + 3][m] = h4[3];
    if (un) {
      *(half4*)(&Yhc[(long)(rowbase + jc) * H + h0 + hc]) = h4;
      if (hc == 0) cmap[jc - jbase] = m;
    }
  }
  __syncthreads();
  // Ytc write: cols [jbase, jbase+nloc), contiguous per row
  {
    const int c = tid & 31;
    if (c < nloc) {
      const int m = cmap[c];
      for (int hh = tid >> 5; hh < 64; hh += 8)
        Ytb[(long)(h0 + hh) * L + jbase + c] = tile[hh][m];
    }
  }
  // pad-zero cols [cnt, cnt32)
  if (m0 == L - 32) {
    const int p = ((cnt + 31) & ~31) - cnt;
    const int c = tid & 31;
    if (c < p)
      for (int hh = tid >> 5; hh < 64; hh += 8)
        Ytb[(long)(h0 + hh) * L + cnt + c] = (f16)0.f;
  }
}

// =====================================================================
// 256x128 tile GEMM (R5-proven schedule, untouched inner loop).
// MODE 0: proj  C[r,1024]=relu(A[r,:]@Wh^T+b) fp16 over contiguous
//         compact rows [Xh ++ Yhc]. Active-tile-balanced XCD swizzle:
//         actWG = ceil((16384+total+32)/256)*8 (multiple of 8), blocks
//         orig >= actWG exit (evenly spread mod 8), active blocks
//         swizzle bijectively over actWG -> every XCD gets Mact tiles.
// MODE 1: scores Sc[b][l,j]=Xp[l,:]@Ypc[j,:]^T f32; col-exit at cnt32.
// MODE 2: PV    out[b][l,h]=Alpha[l,:cnt32]@Ytc[h,:cnt32]^T f32;
//         runtime NT=cnt32/32.
// =====================================================================
#define GLD16(g, l)                                           \
  __builtin_amdgcn_global_load_lds(                           \
      (const __attribute__((address_space(1))) void*)(g),     \
      (__attribute__((address_space(3))) void*)(l), 16, 0, 0)

template <int MODE>
__global__ __launch_bounds__(512, 4) void gemm128(
    const f16* __restrict__ Ap, const f16* __restrict__ Bp,
    const float* __restrict__ bias, void* __restrict__ Cp,
    const int* __restrict__ off17, int nxyShift) {
  __shared__ f16 lds[3 * 12288];  // 3 slots x (A 16KB + B 8KB) = 72 KB
  constexpr int N = 1024, K = 1024;

  const int tid = threadIdx.x;
  const int lane = tid & 63;
  const int wid = tid >> 6;
  const int wm = wid >> 1;
  const int wn = wid & 1;

  const int nwg = gridDim.x;
  const int orig = blockIdx.x;
  int wg;
  if (MODE == 0) {
    const int total = off17[16];
    const int Mact = (16384 + total + 32 + 255) >> 8;
    const int actWG = Mact << 3;  // always a multiple of 8
    if (orig >= actWG) return;
    wg = (orig & 7) * Mact + (orig >> 3);
  } else {
    wg = (orig & 7) * (nwg >> 3) + (orig >> 3);
  }
  const int bz = wg >> nxyShift;
  const int rxy = wg & ((1 << nxyShift) - 1);
  const int bx = rxy & 7;
  const int by = rxy >> 3;
  const int row0 = by * 256, col0 = bx * 128;

  const int srow = lane >> 2;
  const int sslot = (lane & 3) ^ ((lane >> 3) & 3);

  int nt = 32;
  const f16 *gA0, *gA1, *gB0;
  if (MODE == 0) {
    gA0 = Ap + (long)(row0 + wid * 32 + srow) * K + sslot * 8;
    gA1 = gA0 + 16L * K;
    gB0 = Bp + (long)(col0 + wid * 16 + srow) * K + sslot * 8;
  } else if (MODE == 1) {
    const int cnt = off17[bz + 1] - off17[bz];
    if (col0 >= ((cnt + 31) & ~31)) return;
    gA0 = Ap + (long)(bz * 1024 + row0 + wid * 32 + srow) * K + sslot * 8;
    gA1 = gA0 + 16L * K;
    gB0 = Ap + (long)(16384 + off17[bz] + col0 + wid * 16 + srow) * K +
          sslot * 8;
  } else {
    const int cnt = off17[bz + 1] - off17[bz];
    nt = ((cnt + 31) & ~31) >> 5;
    gA0 = Ap + (long)bz * (1 << 20) +
          (long)(row0 + wid * 32 + srow) * 1024 + sslot * 8;
    gA1 = gA0 + 16L * 1024;
    gB0 = Bp + (long)bz * (1 << 20) +
          (long)(col0 + wid * 16 + srow) * 1024 + sslot * 8;
  }
  char* ldsw = (char*)lds;

  const int fr = lane & 15, fq = lane >> 4;
  const int rsw = (fq ^ ((fr >> 1) & 3)) << 4;
  const int aByte = (wm * 64 + fr) * 64 + rsw;
  const int bByte = (wn * 64 + fr) * 64 + rsw;
  const char* ldsr = (const char*)lds;

  f32x4 acc[4][4];
  #pragma unroll
  for (int i = 0; i < 4; ++i)
    #pragma unroll
    for (int j = 0; j < 4; ++j)
      acc[i][j] = (f32x4){0.f, 0.f, 0.f, 0.f};

  #pragma unroll
  for (int p = 0; p < 2; ++p) {
    char* sb = ldsw + p * 24576;
    GLD16(gA0, sb + wid * 2048);
    GLD16(gA1, sb + wid * 2048 + 1024);
    GLD16(gB0, sb + 16384 + wid * 1024);
    gA0 += 32; gA1 += 32; gB0 += 32;
  }
  asm volatile("s_waitcnt vmcnt(3)" ::: "memory");
  __builtin_amdgcn_s_barrier();
  __builtin_amdgcn_sched_barrier(0);

  int cb = 0, pb = 2 * 24576;
  const int NT = (MODE == 2) ? nt : 32;
  for (int t = 0; t < NT; ++t) {
    if (t + 2 < NT) {
      char* sb = ldsw + pb;
      GLD16(gA0, sb + wid * 2048);
      GLD16(gA1, sb + wid * 2048 + 1024);
      GLD16(gB0, sb + 16384 + wid * 1024);
      gA0 += 32; gA1 += 32; gB0 += 32;
    }
    const char* base = ldsr + cb;
    half8 av[4], bv[4];
    #pragma unroll
    for (int j = 0; j < 4; ++j)
      bv[j] = *(const half8*)(base + 16384 + bByte + j * 1024);
    #pragma unroll
    for (int i = 0; i < 4; ++i)
      av[i] = *(const half8*)(base + aByte + i * 1024);
    __builtin_amdgcn_s_setprio(1);
    #pragma unroll
    for (int i = 0; i < 4; ++i)
      #pragma unroll
      for (int j = 0; j < 4; ++j)
        acc[i][j] = __builtin_amdgcn_mfma_f32_16x16x32_f16(av[i], bv[j],
                                                           acc[i][j], 0, 0, 0);
    __builtin_amdgcn_s_setprio(0);
    if (t < NT - 1) {
      __builtin_amdgcn_sched_barrier(0);
      if (t <= NT - 3)
        asm volatile("s_waitcnt vmcnt(3)" ::: "memory");
      else
        asm volatile("s_waitcnt vmcnt(0)" ::: "memory");
      __builtin_amdgcn_s_barrier();
      __builtin_amdgcn_sched_barrier(0);
      cb = (cb == 49152) ? 0 : cb + 24576;
      pb = (pb == 49152) ? 0 : pb + 24576;
    }
  }

  if (MODE == 0) {
    f16* C = (f16*)Cp;
    #pragma unroll
    for (int j = 0; j < 4; ++j) {
      const int col = col0 + wn * 64 + j * 16 + fr;
      const float bvs = bias[col];
      #pragma unroll
      for (int i = 0; i < 4; ++i) {
        const int rowb = row0 + wm * 64 + i * 16 + fq * 4;
        #pragma unroll
        for (int r = 0; r < 4; ++r) {
          float v = acc[i][j][r] + bvs;
          v = v > 0.f ? v : 0.f;
          C[(long)(rowb + r) * N + col] = (f16)v;
        }
      }
    }
  } else {
    float* C = (float*)Cp + (long)bz * (1 << 20);
    #pragma unroll
    for (int j = 0; j < 4; ++j) {
      const int col = col0 + wn * 64 + j * 16 + fr;
      #pragma unroll
      for (int i = 0; i < 4; ++i) {
        const int rowb = row0 + wm * 64 + i * 16 + fq * 4;
        #pragma unroll
        for (int r = 0; r < 4; ++r)
          C[(long)(rowb + r) * N + col] = acc[i][j][r];
      }
    }
  }
}

// ------- masked-compact row softmax: Sc f32 [b][l][j<cnt] -> alpha fp16 -------
__global__ __launch_bounds__(256) void softmax_rows(const float* __restrict__ S,
                                                    const int* __restrict__ off17,
                                                    f16* __restrict__ P) {
  const int b = blockIdx.y;
  const int l = blockIdx.x;
  const int t = threadIdx.x;
  const int cnt = off17[b + 1] - off17[b];
  const int cnt32 = (cnt + 31) & ~31;
  const float* srow = S + ((long)b * L + l) * L;
  f16* prow = P + ((long)b * L + l) * L;

  const float4 v = *(const float4*)(&srow[t * 4]);
  const int j0 = t * 4;
  const float x0 = (j0 + 0 < cnt) ? v.x : -1e30f;
  const float x1 = (j0 + 1 < cnt) ? v.y : -1e30f;
  const float x2 = (j0 + 2 < cnt) ? v.z : -1e30f;
  const float x3 = (j0 + 3 < cnt) ? v.w : -1e30f;

  float mx = fmaxf(fmaxf(x0, x1), fmaxf(x2, x3));
  #pragma unroll
  for (int off = 32; off >= 1; off >>= 1)
    mx = fmaxf(mx, __shfl_xor(mx, off));
  __shared__ float red[8];
  const int wd = t >> 6, lane = t & 63;
  if (lane == 0) red[wd] = mx;
  __syncthreads();
  mx = fmaxf(fmaxf(red[0], red[1]), fmaxf(red[2], red[3]));

  const float e0 = __expf(x0 - mx), e1 = __expf(x1 - mx);
  const float e2 = __expf(x2 - mx), e3 = __expf(x3 - mx);
  float s = e0 + e1 + e2 + e3;
  #pragma unroll
  for (int off = 32; off >= 1; off >>= 1)
    s += __shfl_xor(s, off);
  if (lane == 0) red[4 + wd] = s;
  __syncthreads();
  s = red[4] + red[5] + red[6] + red[7];
  const float inv = 1.f / s;
  const int cnt32b = cnt32;
  if (j0 < cnt32b) {
    half4 h;
    h[0] = (f16)(e0 * inv); h[1] = (f16)(e1 * inv);
    h[2] = (f16)(e2 * inv); h[3] = (f16)(e3 * inv);
    *(half4*)(&prow[j0]) = h;
  }
}

extern "C" void kernel_launch(void* const* d_in, const int* in_sizes, int n_in,
                              void* d_out, int out_size, void* d_ws,
                              size_t ws_size, hipStream_t stream) {
  const float* x = (const float*)d_in[0];
  const float* y = (const float*)d_in[1];
  const int* ymask = (const int*)d_in[2];
  const float* W = (const float*)d_in[3];
  const float* bias = (const float*)d_in[4];
  float* out = (float*)d_out;

  // ws: Wh 2MB | Ytc 32MB | XYp 64MB (meta in tail) | XYh 64MB (Sc alias)
  char* ws = (char*)d_ws;
  f16* Wh = (f16*)(ws);
  f16* Ytc = (f16*)(ws + (1L << 21));
  f16* XYp = (f16*)(ws + (1L << 21) + (1L << 25));
  f16* XYh = (f16*)(ws + (1L << 21) + (1L << 25) + (1L << 26));
  float* Sc = (float*)XYh;  // XYh dead after proj
  f16* Alpha = XYp;         // Xp rows dead after scores

  // meta in XYp tail (rows >= 30720 never touched by proj/scores/alpha)
  char* meta = (char*)XYp + 60L * (1 << 20);
  int* posx = (int*)meta;                  // 64 KB
  int* cntA = (int*)(meta + (1 << 16));    // 64 B
  int* off17 = (int*)(meta + (1 << 16) + 256);

  f16* Xh = XYh;
  f16* Yhc = XYh + (long)BATCH * L * H;  // compact y rows

  cvt_wx<<<512 + 8192, 256, 0, stream>>>(W, Wh, x, Xh);
  mask_scan<<<16, 256, 0, stream>>>(ymask, posx, cntA);
  offsets_k<<<1, 64, 0, stream>>>(cntA, off17);
  transpose_y<<<dim3(16, 32, BATCH), 256, 0, stream>>>(y, ymask, posx, cntA,
                                                       off17, Yhc, Ytc);

  // proj: XYp[r] = relu(XYh[r] @ Wh^T + b), compact contiguous rows
  gemm128<0><<<1024, 512, 0, stream>>>(XYh, Wh, bias, XYp, off17, 10);

  // scores: Sc[b][l][j] = Xp[l] . Ypc[j]
  gemm128<1><<<512, 512, 0, stream>>>(XYp, nullptr, nullptr, Sc, off17, 5);

  // alpha = softmax over j<cnt
  softmax_rows<<<dim3(L, BATCH), 256, 0, stream>>>(Sc, off17, Alpha);

  // out[b][l][h] = sum_j alpha[l][j] * Ytc[h][j]
  gemm128<2><<<512, 512, 0, stream>>>(Alpha, Ytc, nullptr, out, off17, 5);
}